// Round 6
// baseline (881.419 us; speedup 1.0000x reference)
//
#include <hip/hip_runtime.h>
#include <hip/hip_bf16.h>

#define NN_NODES 100000
#define NE_EDGES 1000000
#define D_IN 512
#define D_H0 512
#define D_H1 256
#define D_C  64

using f32x4  = __attribute__((ext_vector_type(4))) float;
using h16x8  = __attribute__((ext_vector_type(8))) _Float16;

// async global->LDS, 16B/lane; LDS dest = wave-uniform base + lane*16
static __device__ __forceinline__ void gll16(const _Float16* g, _Float16* l){
    __builtin_amdgcn_global_load_lds(
        (const __attribute__((address_space(1))) unsigned int*)g,
        (__attribute__((address_space(3))) unsigned int*)l, 16, 0, 0);
}

// raw workgroup barrier with compiler memory fences (no vmcnt(0) drain)
static __device__ __forceinline__ void barrier_f(){
    asm volatile("" ::: "memory");
    __builtin_amdgcn_s_barrier();
    asm volatile("" ::: "memory");
}

// ---------------- fp32 -> fp16, 8 elems/thread ----------------
__global__ __launch_bounds__(256) void tof16_kernel(
    const float* __restrict__ w, _Float16* __restrict__ o, int n8)
{
    int i = blockIdx.x * 256 + threadIdx.x;
    if (i >= n8) return;
    const f32x4 a = *(const f32x4*)(w + (size_t)i * 8);
    const f32x4 b = *(const f32x4*)(w + (size_t)i * 8 + 4);
    h16x8 h;
    #pragma unroll
    for (int j = 0; j < 4; j++){
        h[j]   = (_Float16)a[j];
        h[j+4] = (_Float16)b[j];
    }
    *(h16x8*)(o + (size_t)i * 8) = h;
}

// ---------------- GEMM: C[M,NNc] = act( A[M,K] * B[NNc,K]^T + bias ) ----------------
// fp16 in, fp32 accumulate (mfma_f32_16x16x32_f16).
// 3-buffer LDS pipeline, 2 stages in flight, counted vmcnt (never 0 in steady
// loop), raw barriers, setprio around MFMA cluster.
// LDS XOR-swizzle both-sides: gll dest linear, global chunk pre-permuted
// ((l&3)^((l>>3)&3)); reads use chunk fc^((r>>1)&3) -> conflict-free ds_read_b128.
// OMODE: 1 fp16 out; 2 dual out (O1=v fp32, O2=(v*scale[row]) fp16).
template<bool RELU, int OMODE, int BN_T, int NBN>
__global__ __launch_bounds__(256) void gemm_kernel(
    const _Float16* __restrict__ A,
    const _Float16* __restrict__ B,
    const float* __restrict__ bias,
    void* __restrict__ O1, _Float16* __restrict__ O2, const float* __restrict__ scale,
    int M, int NNc, int K, int xq, int xr)
{
    constexpr int BM = 128, BK = 32;
    constexpr int NF   = BN_T / 32;        // n-fragments per wave
    constexpr int BBLK = BN_T / 16;        // 16-row gll blocks per B tile
    constexpr int TOT  = 8 + BBLK;         // gll ops per k-step (A + B)
    constexpr int LPW  = TOT / 4;          // gll ops per wave per stage

    __shared__ _Float16 sA[3][BM * BK];
    __shared__ _Float16 sB[3][BN_T * BK];

    const int tid  = threadIdx.x;
    const int lane = tid & 63;
    const int wv   = tid >> 6;
    const int wm   = wv >> 1;
    const int wn   = wv & 1;

    // bijective XCD-chunk swizzle (m204)
    const int bid = blockIdx.x;
    const int xcd = bid & 7;
    const int i8  = bid >> 3;
    const int L   = ((xcd < xr) ? xcd * (xq + 1) : xr * (xq + 1) + (xcd - xr) * xq) + i8;
    const int mt  = L / NBN;
    const int bn  = L - mt * NBN;
    const int bm0 = mt * BM;
    const int bn0 = bn * BN_T;

    const int lrow = lane >> 2;                               // row within 16-row block
    const int gch  = ((lane & 3) ^ ((lane >> 3) & 3)) * 8;    // swizzled global chunk (halfs)

    f32x4 acc[4][NF] = {};

    auto stage = [&](int b, int k0){
        #pragma unroll
        for (int t = 0; t < LPW; t++){
            int idx = t * 4 + wv;
            const _Float16* g; _Float16* lb; int rb; int base; int cl;
            if (idx < 8) { g = A; lb = sA[b]; rb = idx;     base = bm0; cl = 1; }
            else         { g = B; lb = sB[b]; rb = idx - 8; base = bn0; cl = 0; }
            int row = base + rb * 16 + lrow;
            if (cl && row > M - 1) row = M - 1;
            gll16(g + (size_t)row * K + k0 + gch, lb + rb * 512);
        }
    };

    auto compute = [&](int b){
        const int fr = lane & 15;
        const int fc = lane >> 4;
        h16x8 bf[NF];
        #pragma unroll
        for (int nf = 0; nf < NF; nf++){
            int r = wn * (BN_T / 2) + nf * 16 + fr;
            int c = (fc ^ ((r >> 1) & 3)) * 8;
            bf[nf] = *(const h16x8*)&sB[b][r * 32 + c];
        }
        h16x8 af[4];
        #pragma unroll
        for (int mf = 0; mf < 4; mf++){
            int r = wm * 64 + mf * 16 + fr;
            int c = (fc ^ ((r >> 1) & 3)) * 8;
            af[mf] = *(const h16x8*)&sA[b][r * 32 + c];
        }
        __builtin_amdgcn_s_setprio(1);
        #pragma unroll
        for (int mf = 0; mf < 4; mf++)
            #pragma unroll
            for (int nf = 0; nf < NF; nf++)
                acc[mf][nf] = __builtin_amdgcn_mfma_f32_16x16x32_f16(af[mf], bf[nf], acc[mf][nf], 0, 0, 0);
        __builtin_amdgcn_s_setprio(0);
    };

    const int NT = K / BK;
    stage(0, 0);
    stage(1, BK);
    for (int t = 0; t < NT; t++){
        if (t + 2 < NT){
            stage((t + 2) % 3, (t + 2) * BK);
            // wait for tile t's loads only: 2 stages (2*LPW loads) stay in flight
            if constexpr (LPW == 4) asm volatile("s_waitcnt vmcnt(8)" ::: "memory");
            else                    asm volatile("s_waitcnt vmcnt(6)" ::: "memory");
        } else if (t + 1 < NT){
            if constexpr (LPW == 4) asm volatile("s_waitcnt vmcnt(4)" ::: "memory");
            else                    asm volatile("s_waitcnt vmcnt(3)" ::: "memory");
        } else {
            asm volatile("s_waitcnt vmcnt(0)" ::: "memory");
        }
        __builtin_amdgcn_s_barrier();       // buf[t%3] complete for all waves
        asm volatile("" ::: "memory");
        compute(t % 3);
        barrier_f();                        // compute done before buf reuse
    }

    // ---- epilogue ----
    #pragma unroll
    for (int mf = 0; mf < 4; mf++){
        #pragma unroll
        for (int nf = 0; nf < NF; nf++){
            #pragma unroll
            for (int r = 0; r < 4; r++){
                int rg = bm0 + wm * 64 + mf * 16 + (lane >> 4) * 4 + r;
                int cg = bn0 + wn * (BN_T / 2) + nf * 16 + (lane & 15);
                if (rg < M){
                    float v = acc[mf][nf][r] + bias[cg];
                    if constexpr (RELU) v = fmaxf(v, 0.f);
                    if constexpr (OMODE == 1)
                        ((_Float16*)O1)[(size_t)rg * NNc + cg] = (_Float16)v;
                    else {
                        ((float*)O1)[(size_t)rg * NNc + cg] = v;
                        O2[(size_t)rg * NNc + cg] = (_Float16)(v * scale[rg]);
                    }
                }
            }
        }
    }
}

// ---------------- graph preprocessing ----------------
__global__ void degrees_kernel(const int* __restrict__ src, const int* __restrict__ dst,
                               int* __restrict__ dout, int* __restrict__ din){
    int e = blockIdx.x * blockDim.x + threadIdx.x;
    if (e < NE_EDGES){
        atomicAdd(&dout[src[e]], 1);
        atomicAdd(&din[dst[e]], 1);
    }
}

__global__ void norm_kernel(const int* __restrict__ dout, const int* __restrict__ din,
                            float* __restrict__ ns, float* __restrict__ nd, int n){
    int i = blockIdx.x * blockDim.x + threadIdx.x;
    if (i < n){
        ns[i] = rsqrtf((float)(dout[i] > 1 ? dout[i] : 1));
        nd[i] = rsqrtf((float)(din[i]  > 1 ? din[i]  : 1));
    }
}

__global__ __launch_bounds__(256) void scan1_kernel(const int* __restrict__ din,
                                                    int* __restrict__ part,
                                                    int* __restrict__ bsum, int n){
    __shared__ int s[256];
    int i = blockIdx.x * 256 + threadIdx.x;
    int v = (i < n) ? din[i] : 0;
    s[threadIdx.x] = v;
    __syncthreads();
    for (int off = 1; off < 256; off <<= 1){
        int t = (threadIdx.x >= off) ? s[threadIdx.x - off] : 0;
        __syncthreads();
        s[threadIdx.x] += t;
        __syncthreads();
    }
    if (i < n) part[i] = s[threadIdx.x];
    if (threadIdx.x == 255) bsum[blockIdx.x] = s[255];
}

__global__ __launch_bounds__(512) void scan2_kernel(int* __restrict__ bsum, int nb){
    __shared__ int s[512];
    int v = (threadIdx.x < nb) ? bsum[threadIdx.x] : 0;
    s[threadIdx.x] = v;
    __syncthreads();
    for (int off = 1; off < 512; off <<= 1){
        int t = (threadIdx.x >= off) ? s[threadIdx.x - off] : 0;
        __syncthreads();
        s[threadIdx.x] += t;
        __syncthreads();
    }
    if (threadIdx.x < nb) bsum[threadIdx.x] = s[threadIdx.x];
}

__global__ void scan3_kernel(const int* __restrict__ part, const int* __restrict__ din,
                             const int* __restrict__ bsum, int* __restrict__ offs,
                             int* __restrict__ cur, int n){
    int i = blockIdx.x * 256 + threadIdx.x;
    if (i < n){
        int base = (blockIdx.x > 0) ? bsum[blockIdx.x - 1] : 0;
        int excl = base + part[i] - din[i];
        offs[i] = excl;
        cur[i]  = excl;
    }
}

__global__ void fill_kernel(const int* __restrict__ src, const int* __restrict__ dst,
                            int* __restrict__ cur, int* __restrict__ csr){
    int e = blockIdx.x * blockDim.x + threadIdx.x;
    if (e < NE_EDGES){
        int d = dst[e];
        int pos = atomicAdd(&cur[d], 1);
        csr[pos] = src[e];
    }
}

// ---------------- APPNP propagation (fp16 gather state) ----------------
__global__ __launch_bounds__(256) void propagate_kernel(
    const _Float16* __restrict__ hs, const float* __restrict__ h0,
    float* __restrict__ hout, _Float16* __restrict__ houts,
    const int* __restrict__ offs, const int* __restrict__ din,
    const int* __restrict__ csr,
    const float* __restrict__ ns, const float* __restrict__ nd)
{
    int wv   = threadIdx.x >> 6;
    int lane = threadIdx.x & 63;
    int grp  = lane >> 3;     // 0..7
    int gl   = lane & 7;      // 0..7
    int node = blockIdx.x * 4 + wv;
    if (node >= NN_NODES) return;
    int start = offs[node];
    int deg   = din[node];
    float acc[8] = {};
    for (int j = grp; j < deg; j += 8){
        int s = csr[start + j];
        h16x8 v = *(const h16x8*)(hs + (size_t)s * D_C + gl * 8);
        #pragma unroll
        for (int i = 0; i < 8; i++) acc[i] += (float)v[i];
    }
    #pragma unroll
    for (int i = 0; i < 8; i++){
        acc[i] += __shfl_xor(acc[i], 8, 64);
        acc[i] += __shfl_xor(acc[i], 16, 64);
        acc[i] += __shfl_xor(acc[i], 32, 64);
    }
    if (grp == 0){
        float ndv = nd[node];
        f32x4 h0a = *(const f32x4*)(h0 + (size_t)node * D_C + gl * 8);
        f32x4 h0b = *(const f32x4*)(h0 + (size_t)node * D_C + gl * 8 + 4);
        float out[8];
        #pragma unroll
        for (int i = 0; i < 4; i++){
            out[i]     = 0.9f * acc[i]     * ndv + 0.1f * h0a[i];
            out[i + 4] = 0.9f * acc[i + 4] * ndv + 0.1f * h0b[i];
        }
        if (hout){
            f32x4 oa, ob;
            #pragma unroll
            for (int i = 0; i < 4; i++){ oa[i] = out[i]; ob[i] = out[i + 4]; }
            *(f32x4*)(hout + (size_t)node * D_C + gl * 8)     = oa;
            *(f32x4*)(hout + (size_t)node * D_C + gl * 8 + 4) = ob;
        }
        if (houts){
            float nsv = ns[node];
            h16x8 o;
            #pragma unroll
            for (int i = 0; i < 8; i++) o[i] = (_Float16)(out[i] * nsv);
            *(h16x8*)(houts + (size_t)node * D_C + gl * 8) = o;
        }
    }
}

// ---------------- launch ----------------
extern "C" void kernel_launch(void* const* d_in, const int* in_sizes, int n_in,
                              void* d_out, int out_size, void* d_ws, size_t ws_size,
                              hipStream_t stream)
{
    const float* features = (const float*)d_in[0];
    const int*   edge     = (const int*)d_in[1];
    const float* W0 = (const float*)d_in[2];
    const float* b0 = (const float*)d_in[3];
    const float* W1 = (const float*)d_in[4];
    const float* b1 = (const float*)d_in[5];
    const float* W2 = (const float*)d_in[6];
    const float* b2 = (const float*)d_in[7];
    const int* src = edge;
    const int* dst = edge + NE_EDGES;

    char* p = (char*)d_ws;
    auto alloc = [&](size_t bytes) -> char* {
        char* r = p;
        p += (bytes + 255) & ~(size_t)255;
        return r;
    };

    const size_t FEAT  = (size_t)NN_NODES * D_IN * 2;   // 102.4 MB fp16
    const size_t HBUF  = (size_t)NN_NODES * D_C * 4;    // 25.6 MB fp32
    const size_t HBUFH = (size_t)NN_NODES * D_C * 2;    // 12.8 MB fp16

    _Float16* w0f = (_Float16*)alloc((size_t)D_H0 * D_IN * 2);
    _Float16* w1f = (_Float16*)alloc((size_t)D_H1 * D_H0 * 2);
    _Float16* w2f = (_Float16*)alloc((size_t)D_C * D_H1 * 2);
    char* R1 = alloc(FEAT);            // fhf; later act2
    char* R2 = alloc(FEAT);            // act1; later h0 + h0s + hAs + hBs
    int*   deg_out = (int*)alloc((size_t)NN_NODES * 4);
    int*   deg_in  = (int*)alloc((size_t)NN_NODES * 4);
    float* nsrc    = (float*)alloc((size_t)NN_NODES * 4);
    float* ndst    = (float*)alloc((size_t)NN_NODES * 4);
    int*   part    = (int*)alloc((size_t)NN_NODES * 4);
    int*   bsum    = (int*)alloc(2048);
    int*   offs    = (int*)alloc((size_t)NN_NODES * 4);
    int*   cur     = (int*)alloc((size_t)NN_NODES * 4);
    int*   csr     = (int*)alloc((size_t)NE_EDGES * 4);
    if ((size_t)(p - (char*)d_ws) > ws_size) return;

    _Float16* fhf  = (_Float16*)R1;          // dead after GEMM1
    _Float16* act2 = (_Float16*)R1;          // written by GEMM2
    _Float16* act1 = (_Float16*)R2;          // dead after GEMM2
    float*    h0  = (float*)R2;              // written by GEMM3
    _Float16* h0s = (_Float16*)(R2 + HBUF);
    _Float16* hAs = (_Float16*)(R2 + HBUF + HBUFH);
    _Float16* hBs = (_Float16*)(R2 + HBUF + 2 * HBUFH);

    // --- graph preprocessing ---
    hipMemsetAsync(deg_out, 0, (size_t)NN_NODES * 4, stream);
    hipMemsetAsync(deg_in,  0, (size_t)NN_NODES * 4, stream);
    degrees_kernel<<<(NE_EDGES + 255) / 256, 256, 0, stream>>>(src, dst, deg_out, deg_in);
    norm_kernel<<<(NN_NODES + 255) / 256, 256, 0, stream>>>(deg_out, deg_in, nsrc, ndst, NN_NODES);
    int nb = (NN_NODES + 255) / 256;
    scan1_kernel<<<nb, 256, 0, stream>>>(deg_in, part, bsum, NN_NODES);
    scan2_kernel<<<1, 512, 0, stream>>>(bsum, nb);
    scan3_kernel<<<nb, 256, 0, stream>>>(part, deg_in, bsum, offs, cur, NN_NODES);
    fill_kernel<<<(NE_EDGES + 255) / 256, 256, 0, stream>>>(src, dst, cur, csr);

    // --- conversions (fp32 -> fp16) ---
    tof16_kernel<<<(NN_NODES * D_IN / 8 + 255) / 256, 256, 0, stream>>>(
        features, fhf, NN_NODES * D_IN / 8);
    tof16_kernel<<<(D_H0 * D_IN / 8 + 255) / 256, 256, 0, stream>>>(W0, w0f, D_H0 * D_IN / 8);
    tof16_kernel<<<(D_H1 * D_H0 / 8 + 255) / 256, 256, 0, stream>>>(W1, w1f, D_H1 * D_H0 / 8);
    tof16_kernel<<<(D_C * D_H1 / 8 + 255) / 256, 256, 0, stream>>>(W2, w2f, D_C * D_H1 / 8);

    // --- MLP ---
    const int mtiles = (NN_NODES + 127) / 128;   // 782
    {   // L0: [100k,512] x [512,512]^T, relu, fp16 out
        int nwg = mtiles * 4;
        gemm_kernel<true, 1, 128, 4><<<nwg, 256, 0, stream>>>(
            fhf, w0f, b0, act1, nullptr, nullptr,
            NN_NODES, D_H0, D_IN, nwg / 8, nwg % 8);
    }
    {   // L1: [100k,512] x [256,512]^T, relu, fp16 out
        int nwg = mtiles * 2;
        gemm_kernel<true, 1, 128, 2><<<nwg, 256, 0, stream>>>(
            act1, w1f, b1, act2, nullptr, nullptr,
            NN_NODES, D_H1, D_H0, nwg / 8, nwg % 8);
    }
    {   // L2: [100k,256] x [64,256]^T, dual out (h0 fp32, h0s=h0*ns fp16)
        int nwg = mtiles;
        gemm_kernel<false, 2, 64, 1><<<nwg, 256, 0, stream>>>(
            act2, w2f, b2, h0, h0s, nsrc,
            NN_NODES, D_C, D_H1, nwg / 8, nwg % 8);
    }

    // --- APPNP: 10 propagation steps ---
    const _Float16* curs = h0s;
    _Float16* bufss[2] = { hAs, hBs };
    int pb = (NN_NODES + 3) / 4;
    for (int it = 0; it < 10; it++){
        float*    out  = (it == 9) ? (float*)d_out : nullptr;
        _Float16* outs = (it == 9) ? nullptr       : bufss[it & 1];
        propagate_kernel<<<pb, 256, 0, stream>>>(curs, h0, out, outs, offs, deg_in, csr, nsrc, ndst);
        curs = outs;
    }
}